// Round 1
// baseline (13351.645 us; speedup 1.0000x reference)
//
#include <hip/hip_runtime.h>

// TimeLSTM on MI355X.
// Decomposition: scan is sequential in S, parallel only in B=64 -> 64 blocks,
// one per batch row (1 CU each). Weights converted to fp16; half the columns
// register-cached, half streamed from L2 each step. v_dot2_f32_f16 for MACs.

#define B_ 64
#define S_ 1024
#define D_ 128
#define H_ 256
#define FH_ 1024          // 4H
#define NROWS_ 1280       // W_all rows (1024) + W_d rows (256)
#define NCH_ 32           // 256 cols / 8 per chunk
#define CACHED_CH_ 16     // chunks 0..15 register-cached in scan

typedef _Float16 half2_t __attribute__((ext_vector_type(2)));
typedef _Float16 half8_t __attribute__((ext_vector_type(8)));

union H8u { half8_t v; half2_t p[4]; };

__device__ inline float dot2acc(half2_t a, half2_t b, float c) {
#if __has_builtin(__builtin_amdgcn_fdot2)
    return __builtin_amdgcn_fdot2(a, b, c, false);
#else
    return c + (float)a[0] * (float)b[0] + (float)a[1] * (float)b[1];
#endif
}

__device__ inline float dot8acc(half8_t a, half8_t b, float c) {
    H8u ua; ua.v = a;
    H8u ub; ub.v = b;
    c = dot2acc(ua.p[0], ub.p[0], c);
    c = dot2acc(ua.p[1], ub.p[1], c);
    c = dot2acc(ua.p[2], ub.p[2], c);
    c = dot2acc(ua.p[3], ub.p[3], c);
    return c;
}

__device__ inline float sigmoid_f(float x) { return 1.f / (1.f + __expf(-x)); }
__device__ inline float tanh_f(float x)    { return 1.f - 2.f / (__expf(2.f * x) + 1.f); }

// ---------------------------------------------------------------------------
// Kernel 0: pack weights to fp16 in chunk-transposed layout.
// WT  : [32 chunks][1280 rows][8 halves]   rows 0..1023 = W_all, 1024..1279 = W_d
// UT  : [16 chunks][1024 k   ][8 halves]   (U_all, D=128 -> 16 chunks)
// Grid: 1792 blocks x 256 threads. Blocks 0..1279 pack WT, 1280..1791 pack UT.
// ---------------------------------------------------------------------------
__global__ __launch_bounds__(256) void pack_weights(
    const float* __restrict__ Wall, const float* __restrict__ Wd,
    const float* __restrict__ Uall,
    _Float16* __restrict__ WT, _Float16* __restrict__ UT)
{
    int blk = blockIdx.x;
    int tid = threadIdx.x;
    if (blk < NROWS_) {
        int r = blk, c = tid;   // r in [0,1280), c in [0,256)
        float v = (r < FH_) ? Wall[(size_t)r * H_ + c] : Wd[(size_t)(r - FH_) * H_ + c];
        WT[((size_t)(c >> 3) * NROWS_ + r) * 8 + (c & 7)] = (_Float16)v;
    } else {
        int idx = (blk - NROWS_) * 256 + tid;   // [0, 131072)
        int k = idx >> 7;        // /128
        int d = idx & 127;
        UT[((size_t)(d >> 3) * FH_ + k) * 8 + (d & 7)] = (_Float16)Uall[(size_t)k * D_ + d];
    }
}

// ---------------------------------------------------------------------------
// Kernel 1: u[b,s,k] = sum_d x[b,s,d] * U[k,d] + Ub[k], stored fp16.
// Block = 16 (b,s)-rows x all 1024 k. Thread handles 4 k's (one per quarter);
// weights (fp16, coalesced) in regs, x row via wave-uniform loads (s_load).
// ---------------------------------------------------------------------------
__global__ __launch_bounds__(256) void u_gemm(
    const float* __restrict__ x, const _Float16* __restrict__ UT,
    const float* __restrict__ Ub, _Float16* __restrict__ u16)
{
    int tid = threadIdx.x;
    size_t row0 = (size_t)blockIdx.x * 16;
    const half8_t* UTv = (const half8_t*)UT;

    #pragma unroll 1
    for (int q = 0; q < 4; q++) {
        int k = q * 256 + tid;
        half8_t w[16];
        #pragma unroll
        for (int i = 0; i < 16; i++) w[i] = UTv[(size_t)i * FH_ + k];
        float bias = Ub[k];
        #pragma unroll 1
        for (int r = 0; r < 16; r++) {
            const float* xr = x + (row0 + r) * D_;   // wave-uniform address
            float acc = bias;
            #pragma unroll
            for (int i = 0; i < 16; i++) {
                #pragma unroll
                for (int e = 0; e < 8; e++)
                    acc += (float)w[i][e] * xr[8 * i + e];   // v_fma_mix
            }
            u16[(row0 + r) * FH_ + k] = (_Float16)acc;
        }
    }
}

// ---------------------------------------------------------------------------
// Kernel 2: the scan. 64 blocks x 512 threads (8 waves/CU, 1 block/CU).
// Thread t owns W_all rows {t, t+512}; thread t<256 additionally owns W_d row t.
// Chunks 0..15 (cols 0..127) of each owned row live in registers; chunks
// 16..31 streamed from L2 each step. h/c as fp16 in LDS, read as half8
// broadcasts. Row mapping: f=rows 0..255, i=256..511, o=512..767, ct=768..1023.
//   t<256 : f_t (row t), o_t (row t+512), c_short_t (W_d row t) -> owns state t
//   t>=256: i_j (row t), ct_j (row t+512), j=t-256 -> exchanged via LDS
// ---------------------------------------------------------------------------
__global__ __launch_bounds__(512, 2) void scan_kernel(
    const float* __restrict__ ts, const _Float16* __restrict__ u16,
    const _Float16* __restrict__ WT,
    const float* __restrict__ Wb, const float* __restrict__ Wdb,
    float* __restrict__ out)
{
    int b = blockIdx.x;
    int t = threadIdx.x;

    __shared__ __align__(16) _Float16 h16[H_];
    __shared__ __align__(16) _Float16 c16[H_];
    __shared__ float iact[H_];
    __shared__ float ctact[H_];

    const half8_t* WTv = (const half8_t*)WT;

    // ---- preload register-cached weight chunks (cols 0..127) ----
    half8_t wa0[CACHED_CH_], wa1[CACHED_CH_], wdv[CACHED_CH_];
    #pragma unroll
    for (int cc = 0; cc < CACHED_CH_; cc++) {
        wa0[cc] = WTv[(size_t)cc * NROWS_ + t];
        wa1[cc] = WTv[(size_t)cc * NROWS_ + t + 512];
    }
    if (t < H_) {
        #pragma unroll
        for (int cc = 0; cc < CACHED_CH_; cc++)
            wdv[cc] = WTv[(size_t)cc * NROWS_ + FH_ + t];
    }
    float wb0 = Wb[t];
    float wb1 = Wb[t + 512];
    float wdb_ = (t < H_) ? Wdb[t] : 0.f;

    if (t < H_) { h16[t] = (_Float16)0.f; c16[t] = (_Float16)0.f; }
    float c_reg = 0.f, h_last = 0.f, c_last = 0.f;
    __syncthreads();

    const float*     tsb  = ts  + (size_t)b * S_;
    const _Float16*  ub   = u16 + (size_t)b * S_ * FH_;
    float*           outb = out + (size_t)b * S_ * H_;

    for (int s = 0; s < S_; s++) {
        float u0 = (float)ub[(size_t)s * FH_ + t];
        float u1 = (float)ub[(size_t)s * FH_ + t + 512];

        const half8_t* hv8 = (const half8_t*)h16;
        const half8_t* cv8 = (const half8_t*)c16;

        float a0 = 0.f, a1 = 0.f, ad = 0.f;
        // register-cached half (cols 0..127)
        #pragma unroll 4
        for (int cc = 0; cc < CACHED_CH_; cc++) {
            half8_t hv = hv8[cc];
            a0 = dot8acc(hv, wa0[cc], a0);
            a1 = dot8acc(hv, wa1[cc], a1);
        }
        // streamed half (cols 128..255) from L2
        #pragma unroll 2
        for (int cc = CACHED_CH_; cc < NCH_; cc++) {
            half8_t hv = hv8[cc];
            half8_t w0 = WTv[(size_t)cc * NROWS_ + t];
            half8_t w1 = WTv[(size_t)cc * NROWS_ + t + 512];
            a0 = dot8acc(hv, w0, a0);
            a1 = dot8acc(hv, w1, a1);
        }
        if (t < H_) {
            #pragma unroll 4
            for (int cc = 0; cc < CACHED_CH_; cc++)
                ad = dot8acc(cv8[cc], wdv[cc], ad);
            #pragma unroll 2
            for (int cc = CACHED_CH_; cc < NCH_; cc++) {
                half8_t w2 = WTv[(size_t)cc * NROWS_ + FH_ + t];
                ad = dot8acc(cv8[cc], w2, ad);
            }
        }

        float pre0 = a0 + wb0 + u0;
        float pre1 = a1 + wb1 + u1;

        if (t >= H_) {
            iact[t - H_]  = sigmoid_f(pre0);   // i gate
            ctact[t - H_] = tanh_f(pre1);      // c_tmp
        }
        __syncthreads();
        if (t < H_) {
            float dly;
            if (s == 0) dly = 1.f;
            else {
                float dt = tsb[s] - tsb[s - 1];
                dt = fmaxf(dt, 1e-6f);
                dly = 1.f / logf(2.718281828459045f + dt);
            }
            float cs   = tanh_f(ad + wdb_);
            float cadj = (c_reg - cs) + cs * dly;
            float fg   = sigmoid_f(pre0);
            float og   = sigmoid_f(pre1);
            float cn   = fg * cadj + iact[t] * ctact[t];
            float hn   = og * tanh_f(cn);
            c_reg = cn; h_last = hn; c_last = cn;
            outb[(size_t)s * H_ + t] = hn;
            h16[t] = (_Float16)hn;
            c16[t] = (_Float16)cn;
        }
        __syncthreads();
    }

    if (t < H_) {
        out[(size_t)B_ * S_ * H_ + (size_t)b * H_ + t] = h_last;
        out[(size_t)B_ * S_ * H_ + (size_t)B_ * H_ + (size_t)b * H_ + t] = c_last;
    }
}

// ---------------------------------------------------------------------------
extern "C" void kernel_launch(void* const* d_in, const int* in_sizes, int n_in,
                              void* d_out, int out_size, void* d_ws, size_t ws_size,
                              hipStream_t stream) {
    const float* inputs     = (const float*)d_in[0];   // [B,S,D]
    const float* timestamps = (const float*)d_in[1];   // [B,S]
    const float* W_all_w    = (const float*)d_in[2];   // [4H,H]
    const float* W_all_b    = (const float*)d_in[3];   // [4H]
    const float* U_all_w    = (const float*)d_in[4];   // [4H,D]
    const float* U_all_b    = (const float*)d_in[5];   // [4H]
    const float* W_d_w      = (const float*)d_in[6];   // [H,H]
    const float* W_d_b      = (const float*)d_in[7];   // [H]
    float* out = (float*)d_out;

    // workspace layout
    _Float16* u16 = (_Float16*)d_ws;                                   // 128 MiB
    _Float16* WT  = (_Float16*)((char*)d_ws + (size_t)B_ * S_ * FH_ * 2);  // 640 KiB
    _Float16* UT  = (_Float16*)((char*)WT + (size_t)NCH_ * NROWS_ * 8 * 2); // 256 KiB

    pack_weights<<<dim3(NROWS_ + 512), dim3(256), 0, stream>>>(
        W_all_w, W_d_w, U_all_w, WT, UT);
    u_gemm<<<dim3(B_ * S_ / 16), dim3(256), 0, stream>>>(
        inputs, UT, U_all_b, u16);
    scan_kernel<<<dim3(B_), dim3(512), 0, stream>>>(
        timestamps, u16, WT, W_all_b, W_d_b, out);
}

// Round 2
// 6729.654 us; speedup vs baseline: 1.9840x; 1.9840x over previous
//
#include <hip/hip_runtime.h>

// TimeLSTM on MI355X (gfx950).
// B=64,S=1024,D=128,H=256. Scan: 64 blocks (1 batch row/CU), 256 threads.
// Thread t owns gate rows t,t+256,t+512,t+768 and W_d row t -> all gates for
// state element t in one thread; one barrier/step; h/c ping-pong in LDS.
// fp16 weights: 108 chunks/thread in VGPRs (FULL unroll - round-1 bug was
// partial unroll forcing scratch), 12 chunks in LDS, 40 chunks streamed from
// L2 per step. u precomputed by an MFMA GEMM, stored gate-interleaved.

#define B_ 64
#define S_ 1024
#define D_ 128
#define H_ 256
#define FH_ 1024          // 4H
#define NROWS_ 1280       // 1024 W_all rows + 256 W_d rows

typedef _Float16 half2_t __attribute__((ext_vector_type(2)));
typedef _Float16 half4_t __attribute__((ext_vector_type(4)));
typedef _Float16 half8_t __attribute__((ext_vector_type(8)));
typedef float    f32x4   __attribute__((ext_vector_type(4)));

union H8u { half8_t v; half2_t p[4]; };

__device__ inline float dot2acc(half2_t a, half2_t b, float c) {
#if __has_builtin(__builtin_amdgcn_fdot2)
    return __builtin_amdgcn_fdot2(a, b, c, false);
#else
    return c + (float)a[0] * (float)b[0] + (float)a[1] * (float)b[1];
#endif
}

__device__ inline float dot8acc(half8_t a, half8_t b, float c) {
    H8u ua; ua.v = a;
    H8u ub; ub.v = b;
    c = dot2acc(ua.p[0], ub.p[0], c);
    c = dot2acc(ua.p[1], ub.p[1], c);
    c = dot2acc(ua.p[2], ub.p[2], c);
    c = dot2acc(ua.p[3], ub.p[3], c);
    return c;
}

__device__ inline float sigmoid_f(float x) { return 1.f / (1.f + __expf(-x)); }
__device__ inline float tanh_f(float x)    { return 1.f - 2.f / (__expf(2.f * x) + 1.f); }

// ---------------------------------------------------------------------------
// Pack: WT fp16 chunk-transposed [32][1280][8]; U16 fp16 row-major [1024][128];
// decay fp32 [64][1024]. Grid 2048 x 256.
// ---------------------------------------------------------------------------
__global__ __launch_bounds__(256) void pack_kernel(
    const float* __restrict__ Wall, const float* __restrict__ Wd,
    const float* __restrict__ Uall, const float* __restrict__ ts,
    _Float16* __restrict__ WT, _Float16* __restrict__ U16,
    float* __restrict__ decay)
{
    int idx = blockIdx.x * 256 + threadIdx.x;
    if (idx < 327680) {
        int r = idx >> 8, c = idx & 255;
        float v = (r < FH_) ? Wall[(size_t)r * H_ + c]
                            : Wd[(size_t)(r - FH_) * H_ + c];
        WT[((size_t)(c >> 3) * NROWS_ + r) * 8 + (c & 7)] = (_Float16)v;
    } else if (idx < 327680 + 131072) {
        int i = idx - 327680;
        U16[i] = (_Float16)Uall[i];
    } else {
        int i = idx - 458752;                // [0, 65536)
        int bb = i >> 10, s = i & 1023;
        float d = 1.f;
        if (s > 0) {
            float dt = ts[bb * S_ + s] - ts[bb * S_ + s - 1];
            dt = fmaxf(dt, 1e-6f);
            d = 1.f / logf(2.718281828459045f + dt);
        }
        decay[i] = d;
    }
}

// ---------------------------------------------------------------------------
// u GEMM via MFMA 16x16x32 f16: [65536x128] @ [128x1024]^T(row-major U[n][k]).
// Grid (1024 m-blocks, 4 n-blocks) x 256 thr (4 waves; wave = 16 rows x 256 n).
// A-frag: lane holds x[row0 + (lane&15)][kc*32 + (lane>>4)*8 + j] (cvt fp32->fp16).
// B-frag: lane holds U[n0+nt*16+(lane&15)][kc*32 + (lane>>4)*8 + j].
// D: col=lane&15, row=(lane>>4)*4+i. Store gate-interleaved: [row][e*4+g].
// ---------------------------------------------------------------------------
__global__ __launch_bounds__(256) void u_gemm_mfma(
    const float* __restrict__ x, const _Float16* __restrict__ U16,
    const float* __restrict__ Ub, _Float16* __restrict__ u16)
{
    int wave = threadIdx.x >> 6, lane = threadIdx.x & 63;
    size_t row0 = (size_t)blockIdx.x * 64 + wave * 16;
    int n0 = blockIdx.y * 256;
    int am = lane & 15;
    int ak = (lane >> 4) * 8;
    const float* xr = x + (row0 + am) * D_ + ak;

    f32x4 acc[16];
    #pragma unroll
    for (int nt = 0; nt < 16; nt++) acc[nt] = (f32x4){0.f, 0.f, 0.f, 0.f};

    #pragma unroll
    for (int kc = 0; kc < 4; kc++) {
        f16x8_decl:;
        half8_t a;
        #pragma unroll
        for (int e = 0; e < 8; e++) a[e] = (_Float16)xr[kc * 32 + e];
        #pragma unroll
        for (int nt = 0; nt < 16; nt++) {
            half8_t bfr = *(const half8_t*)(U16 + (size_t)(n0 + nt * 16 + am) * D_ + kc * 32 + ak);
            acc[nt] = __builtin_amdgcn_mfma_f32_16x16x32_f16(a, bfr, acc[nt], 0, 0, 0);
        }
    }

    int cr = (lane >> 4) * 4;
    #pragma unroll
    for (int nt = 0; nt < 16; nt++) {
        int col = n0 + nt * 16 + am;
        float bias = Ub[col];
        int e = col & 255, g = col >> 8;
        #pragma unroll
        for (int i = 0; i < 4; i++) {
            u16[(row0 + cr + i) * (size_t)FH_ + e * 4 + g] = (_Float16)(acc[nt][i] + bias);
        }
    }
}

// ---------------------------------------------------------------------------
// Scan. 64 blocks x 256 threads. Thread t: rows t (f), t+256 (i), t+512 (o),
// t+768 (ct) of W_all + W_d row t. Register weights: w0,w1,w2 (rows t,t+256,
// t+512; 96 chunks) + wdr (W_d chunks 12..23) = 432 VGPR. LDS: W_d chunks
// 0..11 (49KB). Streamed from L2 each step: row t+768 (32) + W_d 24..31 (8).
// ---------------------------------------------------------------------------
__global__ __launch_bounds__(256, 1) void scan_kernel(
    const _Float16* __restrict__ u16, const _Float16* __restrict__ WT,
    const float* __restrict__ Wb, const float* __restrict__ Wdb,
    const float* __restrict__ decay, float* __restrict__ out)
{
    int b = blockIdx.x;
    int t = threadIdx.x;

    __shared__ __align__(16) _Float16 hbuf[2][H_];
    __shared__ __align__(16) _Float16 cbuf[2][H_];
    __shared__ half8_t wl[12][H_];               // W_d chunks 0..11, 49152 B

    const half8_t* __restrict__ WTv = (const half8_t*)WT;

    // ---- register weights: FULL unroll, constant indices only ----
    half8_t w0[32], w1[32], w2[32], wdr[12];
    #pragma unroll
    for (int cc = 0; cc < 32; cc++) {
        w0[cc] = WTv[(size_t)cc * NROWS_ + t];
        w1[cc] = WTv[(size_t)cc * NROWS_ + 256 + t];
        w2[cc] = WTv[(size_t)cc * NROWS_ + 512 + t];
    }
    #pragma unroll
    for (int j = 0; j < 12; j++) wdr[j] = WTv[(size_t)(12 + j) * NROWS_ + FH_ + t];
    #pragma unroll
    for (int j = 0; j < 12; j++) wl[j][t] = WTv[(size_t)j * NROWS_ + FH_ + t];

    float wbf = Wb[t], wbi = Wb[256 + t], wbo = Wb[512 + t], wbc = Wb[768 + t];
    float wdbt = Wdb[t];

    hbuf[0][t] = (_Float16)0.f;
    cbuf[0][t] = (_Float16)0.f;
    float c_reg = 0.f, hn = 0.f;
    __syncthreads();

    const _Float16* __restrict__ ub   = u16 + (size_t)b * S_ * FH_;
    const float*    __restrict__ db   = decay + (size_t)b * S_;
    float*          __restrict__ outb = out + (size_t)b * S_ * H_;

    for (int s = 0; s < S_; s++) {
        int cur = s & 1;
        const half8_t* hc  = (const half8_t*)hbuf[cur];
        const half8_t* cc8 = (const half8_t*)cbuf[cur];

        half4_t u4 = *(const half4_t*)(ub + (size_t)s * FH_ + t * 4);
        float dly = db[s];

        float af = 0.f, ai = 0.f, ao = 0.f, ac = 0.f, ad = 0.f;
        float af2 = 0.f, ai2 = 0.f, ao2 = 0.f, ac2 = 0.f, ad2 = 0.f;

        #pragma unroll
        for (int cc = 0; cc < 32; cc++) {
            half8_t h8 = hc[cc];
            half8_t c8 = cc8[cc];
            half8_t w3 = WTv[(size_t)cc * NROWS_ + 768 + t];          // streamed
            half8_t wd = (cc < 12) ? wl[cc][t]
                       : (cc < 24) ? wdr[cc - 12]
                                   : WTv[(size_t)cc * NROWS_ + FH_ + t];  // streamed
            if (cc & 1) {
                af2 = dot8acc(h8, w0[cc], af2);
                ai2 = dot8acc(h8, w1[cc], ai2);
                ao2 = dot8acc(h8, w2[cc], ao2);
                ac2 = dot8acc(h8, w3, ac2);
                ad2 = dot8acc(c8, wd, ad2);
            } else {
                af = dot8acc(h8, w0[cc], af);
                ai = dot8acc(h8, w1[cc], ai);
                ao = dot8acc(h8, w2[cc], ao);
                ac = dot8acc(h8, w3, ac);
                ad = dot8acc(c8, wd, ad);
            }
        }

        float pf = af + af2 + wbf + (float)u4[0];
        float pi = ai + ai2 + wbi + (float)u4[1];
        float po = ao + ao2 + wbo + (float)u4[2];
        float pc = ac + ac2 + wbc + (float)u4[3];

        float cs   = tanh_f(ad + ad2 + wdbt);
        float cadj = (c_reg - cs) + cs * dly;
        float cn   = sigmoid_f(pf) * cadj + sigmoid_f(pi) * tanh_f(pc);
        hn = sigmoid_f(po) * tanh_f(cn);
        c_reg = cn;

        outb[(size_t)s * H_ + t] = hn;
        int nxt = cur ^ 1;
        hbuf[nxt][t] = (_Float16)hn;
        cbuf[nxt][t] = (_Float16)cn;
        __syncthreads();
    }

    out[(size_t)B_ * S_ * H_ + (size_t)b * H_ + t] = hn;
    out[(size_t)B_ * S_ * H_ + (size_t)B_ * H_ + (size_t)b * H_ + t] = c_reg;
}

// ---------------------------------------------------------------------------
extern "C" void kernel_launch(void* const* d_in, const int* in_sizes, int n_in,
                              void* d_out, int out_size, void* d_ws, size_t ws_size,
                              hipStream_t stream) {
    const float* inputs     = (const float*)d_in[0];   // [B,S,D]
    const float* timestamps = (const float*)d_in[1];   // [B,S]
    const float* W_all_w    = (const float*)d_in[2];   // [4H,H]
    const float* W_all_b    = (const float*)d_in[3];   // [4H]
    const float* U_all_w    = (const float*)d_in[4];   // [4H,D]
    const float* U_all_b    = (const float*)d_in[5];   // [4H]
    const float* W_d_w      = (const float*)d_in[6];   // [H,H]
    const float* W_d_b      = (const float*)d_in[7];   // [H]
    float* out = (float*)d_out;

    // workspace layout
    char* p = (char*)d_ws;
    _Float16* u16 = (_Float16*)p;                 p += (size_t)B_ * S_ * FH_ * 2;   // 134217728
    _Float16* WT  = (_Float16*)p;                 p += (size_t)32 * NROWS_ * 8 * 2; // 655360
    _Float16* U16 = (_Float16*)p;                 p += (size_t)FH_ * D_ * 2;        // 262144
    float*    dec = (float*)p;                                                       // 262144

    pack_kernel<<<dim3(2048), dim3(256), 0, stream>>>(
        W_all_w, W_d_w, U_all_w, timestamps, WT, U16, dec);
    u_gemm_mfma<<<dim3(1024, 4), dim3(256), 0, stream>>>(
        inputs, U16, U_all_b, u16);
    scan_kernel<<<dim3(B_), dim3(256), 0, stream>>>(
        u16, WT, W_all_b, W_d_b, dec, out);
}